// Round 1
// baseline (1272.190 us; speedup 1.0000x reference)
//
#include <hip/hip_runtime.h>

// ---------------------------------------------------------------------------
// Fused zero-state-LSTM + softmax for MI355X (gfx950).
//
//   xs[b, s', i'] = x[b, 3*(s'%80)+i'/60, i'%60, s'/80]   (permute+reshape)
//   gates = xs @ W_ih^T + b_ih + b_hh   (h0 == 0 -> W_hh dead; f-gate dead)
//   h = sig(o) * tanh( sig(i) * tanh(g) );  out = softmax_h(h)
//
// Single kernel: M-tile 128 rows x N 576 (3 gate chunks of 192, cols 180..191
// zero-padded), K padded 180->192, 6 k-slices of 32 staged to LDS with
// on-the-fly fp32->bf16 convert. 512 threads = 8 waves; wave w owns rows
// w*16..w*16+15 completely (all i/g/o cols) so softmax is wave-local.
// MFMA 16x16x32 bf16 (m89/m91-verified layouts).
// ---------------------------------------------------------------------------

typedef __attribute__((ext_vector_type(8))) short short8;   // 8 bf16 = 4 VGPR
typedef __attribute__((ext_vector_type(4))) float float4v;  // MFMA acc

#define SEQ   240
#define HID   180
#define NROWS (2048 * SEQ)       // 491520
#define MT    128
#define NBLK  (NROWS / MT)       // 3840
#define NP    576                // padded N (3 chunks of 192)
#define LSTR  40                 // LDS row stride in bf16 (80 B: 2-way banks, 16B aligned)

__device__ __forceinline__ unsigned short f2bf(float f) {
    unsigned int u = __float_as_uint(f);
    u += 0x7fffu + ((u >> 16) & 1u);   // round-to-nearest-even
    return (unsigned short)(u >> 16);
}
__device__ __forceinline__ float fast_sig(float x) {
    return __builtin_amdgcn_rcpf(1.0f + __expf(-x));
}
__device__ __forceinline__ float fast_tanh(float x) {
    // 1 - 2/(e^{2x}+1): exact at +/-inf, ~1e-6 rel error
    return 1.0f - 2.0f * __builtin_amdgcn_rcpf(__expf(2.0f * x) + 1.0f);
}

__global__ __launch_bounds__(512) void lstm_softmax_kernel(
        const float* __restrict__ x, const float* __restrict__ Wih,
        const float* __restrict__ b_ih, const float* __restrict__ b_hh,
        float* __restrict__ out) {
    __shared__ short A_sl[MT * LSTR];    // 10,240 B
    __shared__ short B_sl[NP * LSTR];    // 46,080 B
    __shared__ float biasS[NP];          //  2,304 B  (total 58,624 B -> 2 blk/CU)

    const int t = threadIdx.x;

    // XCD swizzle: consecutive virtual blocks land on the same XCD so the two
    // blocks sharing one batch's x[b] dedupe in that XCD's L2.
    const int raw = blockIdx.x;
    const int vb  = (raw & 7) * (NBLK / 8) + (raw >> 3);
    const int r0  = vb * MT;

    // ---- bias (b_ih + b_hh) for used gates i/g/o into LDS; pad cols -> 0 ----
    for (int i = t; i < NP; i += 512) {
        const int chunk = i / 192, off = i - chunk * 192;
        float bv = 0.0f;
        if (off < HID) {
            const int g = (chunk == 0 ? 0 : (chunk == 1 ? 360 : 540)) + off;
            bv = b_ih[g] + b_hh[g];
        }
        biasS[i] = bv;
    }

    // ---- A-staging invariants: thread -> (row_l = t>>2, seg = t&3) ----
    const int row_l = t >> 2;
    const int seg   = t & 3;
    const int grow  = r0 + row_l;            // global row = b*240 + s'
    const int bb    = grow / SEQ;
    const int sp    = grow - bb * SEQ;       // s'
    const int cc    = sp / 80;               // channel 0..2
    const int sb    = 3 * (sp - cc * 80);    // base s in x
    const float* xrow = x + (size_t)bb * (SEQ * HID) + cc;

    float4v acc[36];
#pragma unroll
    for (int j = 0; j < 36; ++j) acc[j] = (float4v){0.f, 0.f, 0.f, 0.f};

    const int lane = t & 63;
    const int wid  = t >> 6;    // wave 0..7 -> rows wid*16..+15
    const int ln   = lane & 15;
    const int q    = lane >> 4;

    for (int kk = 0; kk < 6; ++kk) {
        __syncthreads();   // previous iter's frag reads done before restage

        // ---- stage A slice [128][32]: gather x with permute, cvt bf16 ----
        {
            const int k0 = kk * 32 + seg * 8;
            short8 sv;
#pragma unroll
            for (int j = 0; j < 8; ++j) {
                const int k = k0 + j;
                float f = 0.0f;
                if (k < HID) {                      // zero-pad K 180..191
                    const int tt = k / 60;          // const-div, cheap
                    const int w  = k - tt * 60;
                    f = xrow[(sb + tt) * HID + w * 3];
                }
                sv[j] = (short)f2bf(f);
            }
            *(short8*)(&A_sl[row_l * LSTR + seg * 8]) = sv;
        }

        // ---- stage B slice (W_ih rows as B^T) [576][32] ----
        for (int i = t; i < NP * 4; i += 512) {
            const int n  = i >> 2;
            const int sg = i & 3;
            const int k0 = kk * 32 + sg * 8;
            const int chunk = n / 192, off = n - chunk * 192;
            short8 sv;
            if (off < HID) {
                const int g = (chunk == 0 ? 0 : (chunk == 1 ? 360 : 540)) + off;
                const float* wr = Wih + (size_t)g * HID;
#pragma unroll
                for (int j = 0; j < 8; ++j) {
                    float f = 0.0f;
                    const int k = k0 + j;
                    if (k < HID) f = wr[k];
                    sv[j] = (short)f2bf(f);
                }
            } else {
#pragma unroll
                for (int j = 0; j < 8; ++j) sv[j] = 0;
            }
            *(short8*)(&B_sl[n * LSTR + sg * 8]) = sv;
        }
        __syncthreads();

        // ---- MFMA: wave = 16 rows x 36 n-tiles ----
        // A frag: A[m=ln][k=q*8+j];  B frag: B^T[n=ln][k=q*8+j]
        const short8 a = *(const short8*)(&A_sl[(wid * 16 + ln) * LSTR + q * 8]);
#pragma unroll
        for (int j = 0; j < 36; ++j) {
            const short8 bf = *(const short8*)(&B_sl[(j * 16 + ln) * LSTR + q * 8]);
            acc[j] = __builtin_amdgcn_mfma_f32_16x16x32_bf16(a, bf, acc[j], 0, 0, 0);
        }
    }

    // ---- epilogue: C[m = q*4+reg][n = 16*j+ln]; wave-local softmax ----
    const int out_row_base = r0 + wid * 16 + q * 4;
#pragma unroll
    for (int reg = 0; reg < 4; ++reg) {
        const int row = out_row_base + reg;
        float ev[12];
        float hmax = -3.0e38f;
#pragma unroll
        for (int j = 0; j < 12; ++j) {
            const int h = j * 16 + ln;              // hid index (pad if >=180)
            const float gi = acc[j][reg]      + biasS[h];
            const float gg = acc[j + 12][reg] + biasS[192 + h];
            const float go = acc[j + 24][reg] + biasS[384 + h];
            const float cell = fast_sig(gi) * fast_tanh(gg);
            float hv = fast_sig(go) * fast_tanh(cell);
            hv = (h < HID) ? hv : -3.0e38f;
            ev[j] = hv;
            hmax = fmaxf(hmax, hv);
        }
#pragma unroll
        for (int m = 1; m < 16; m <<= 1) hmax = fmaxf(hmax, __shfl_xor(hmax, m, 16));
        float ssum = 0.0f;
#pragma unroll
        for (int j = 0; j < 12; ++j) {
            const int h = j * 16 + ln;
            const float e = (h < HID) ? __expf(ev[j] - hmax) : 0.0f;
            ev[j] = e;
            ssum += e;
        }
#pragma unroll
        for (int m = 1; m < 16; m <<= 1) ssum += __shfl_xor(ssum, m, 16);
        const float inv = __builtin_amdgcn_rcpf(ssum);
        float* __restrict__ orow = out + (size_t)row * HID;
#pragma unroll
        for (int j = 0; j < 12; ++j) {
            const int h = j * 16 + ln;
            if (h < HID) orow[h] = ev[j] * inv;
        }
    }
}

extern "C" void kernel_launch(void* const* d_in, const int* in_sizes, int n_in,
                              void* d_out, int out_size, void* d_ws, size_t ws_size,
                              hipStream_t stream) {
    const float* x    = (const float*)d_in[0];
    const float* Wih  = (const float*)d_in[1];
    // d_in[2] = W_hh: dead (h0 == 0)
    const float* b_ih = (const float*)d_in[3];
    const float* b_hh = (const float*)d_in[4];
    float* out = (float*)d_out;
    hipLaunchKernelGGL(lstm_softmax_kernel, dim3(NBLK), dim3(512), 0, stream,
                       x, Wih, b_ih, b_hh, out);
}